// Round 7
// baseline (285.099 us; speedup 1.0000x reference)
//
#include <hip/hip_runtime.h>

#define NCLS 128
#define HLVL 4
#define BLOCKS 2048
#define BCHUNK 4096            // float4 per array per block (64 KB)
#define STAGE 512              // float4 per array per stage (8 KB)
#define NSTAGE (BCHUNK / STAGE)

typedef const __attribute__((address_space(1))) void* gas_t;
typedef __attribute__((address_space(3))) void* las_t;

// s_waitcnt with vmcnt(n), expcnt/lgkmcnt don't-care (gfx9 encoding)
#define WCNT(n) __builtin_amdgcn_s_waitcnt(((n) & 15) | 0x70 | 0xF00 | (((n) >> 4) << 14))

// Prep: w[c] = (1/128) * sum_l La[l,c] * lam[l] into d_ws[0..127].
__global__ void prep_kernel(const float* __restrict__ La,
                            const float* __restrict__ lam,
                            float* __restrict__ w) {
    int c = threadIdx.x;
    if (c < NCLS) {
        float acc = 0.f;
#pragma unroll
        for (int l = 0; l < HLVL; ++l) acc += La[l * NCLS + c] * lam[l];
        w[c] = acc * (1.0f / (float)NCLS);
    }
}

// R7: global_load_lds DMA staging to bypass the L1/VGPR return path
// (R6 evidence: read cap ~3 TB/s is CU-local — nt helps, MLP doesn't;
// consistent with L1 MSHR limit; writes/fills do 7 TB/s).
// Each lane DMAs 16 B to wave-uniform-base + lane*16 and later reads back
// ONLY its own 16 B -> wave-local ordering, no __syncthreads anywhere.
// Double-buffered stages, manual vmcnt(4) keeps next stage in flight.
//   t*softplus(-x) + (1-t)*softplus(x) = log1p(exp(-|x|)) + max(x,0) - t*x
//   log1p(exp(-a)) = ln2 * log2(1 + 2^(-a*log2e))  -> v_exp_f32 + v_log_f32
// All global index strides are multiples of 128 floats -> each thread's 4
// class weights are loop-invariant registers.
__global__ __launch_bounds__(256) void loss_kernel(const float4* __restrict__ yp,
                                                   const float4* __restrict__ yt,
                                                   const float* __restrict__ w,
                                                   float* __restrict__ partial) {
    __shared__ float4 lds[2][2][STAGE];    // [buf][array][512] = 32 KB
    const float LOG2E = 1.44269504088896340736f;
    const float LN2   = 0.69314718055994530942f;

    int t = threadIdx.x;
    int wbase = t & ~63;                   // wave*64 (wave-uniform)
    long gbase = (long)blockIdx.x * BCHUNK;

    int cbase = (t * 4) & (NCLS - 1);      // loop-invariant class offset
    float4 w4 = *(const float4*)(w + cbase);
    float wv[4] = {w4.x, w4.y, w4.z, w4.w};
    float wl[4] = {w4.x * LN2, w4.y * LN2, w4.z * LN2, w4.w * LN2};

    // issue stage s into buffer s&1: 4 DMA instrs (2 rounds x 2 arrays)
    auto issue = [&](int s) {
        int buf = s & 1;
#pragma unroll
        for (int r = 0; r < 2; ++r) {
            const float4* g0 = yp + gbase + s * STAGE + r * 256 + t;
            const float4* g1 = yt + gbase + s * STAGE + r * 256 + t;
            __builtin_amdgcn_global_load_lds((gas_t)g0,
                (las_t)&lds[buf][0][r * 256 + wbase], 16, 0, 0);
            __builtin_amdgcn_global_load_lds((gas_t)g1,
                (las_t)&lds[buf][1][r * 256 + wbase], 16, 0, 0);
        }
    };

    float acc[4] = {0.f, 0.f, 0.f, 0.f};
    issue(0);
#pragma unroll
    for (int s = 0; s < NSTAGE; ++s) {
        if (s + 1 < NSTAGE) { issue(s + 1); WCNT(4); }  // stage s done, s+1 flying
        else                { WCNT(0); }
        __asm__ volatile("" ::: "memory");
        int buf = s & 1;
#pragma unroll
        for (int r = 0; r < 2; ++r) {
            float4 x4 = lds[buf][0][r * 256 + t];
            float4 t4 = lds[buf][1][r * 256 + t];
            float xs[4] = {x4.x, x4.y, x4.z, x4.w};
            float ts[4] = {t4.x, t4.y, t4.z, t4.w};
#pragma unroll
            for (int j = 0; j < 4; ++j) {
                float xv = xs[j];
                float e  = __builtin_amdgcn_exp2f(-fabsf(xv) * LOG2E);
                float l2 = __builtin_amdgcn_logf(1.0f + e);
                float rr = fmaf(-ts[j], xv, fmaxf(xv, 0.f));
                acc[j] = fmaf(l2, wl[j], acc[j]);
                acc[j] = fmaf(rr, wv[j], acc[j]);
            }
        }
        __asm__ volatile("" ::: "memory");
    }
    float a = (acc[0] + acc[1]) + (acc[2] + acc[3]);

    // wave-64 shuffle reduction
#pragma unroll
    for (int off = 32; off > 0; off >>= 1)
        a += __shfl_down(a, off, 64);

    __shared__ float bsum[4];  // 256 threads = 4 waves
    if ((t & 63) == 0) bsum[t >> 6] = a;
    __syncthreads();
    if (t == 0)
        partial[blockIdx.x] = (bsum[0] + bsum[1]) + (bsum[2] + bsum[3]);
}

// Final: reduce BLOCKS partials -> out[0].
__global__ __launch_bounds__(256) void final_kernel(const float* __restrict__ partial,
                                                    float* __restrict__ out) {
    int t = threadIdx.x;
    float a = 0.f;
#pragma unroll
    for (int k = 0; k < BLOCKS / 256; ++k)
        a += partial[t + k * 256];
#pragma unroll
    for (int off = 32; off > 0; off >>= 1)
        a += __shfl_down(a, off, 64);
    __shared__ float bsum[4];
    if ((t & 63) == 0) bsum[t >> 6] = a;
    __syncthreads();
    if (t == 0)
        out[0] = (bsum[0] + bsum[1]) + (bsum[2] + bsum[3]);
}

extern "C" void kernel_launch(void* const* d_in, const int* in_sizes, int n_in,
                              void* d_out, int out_size, void* d_ws, size_t ws_size,
                              hipStream_t stream) {
    const float* y_pred = (const float*)d_in[0];
    const float* y_true = (const float*)d_in[1];
    const float* La     = (const float*)d_in[2];
    const float* lam    = (const float*)d_in[3];
    float* out = (float*)d_out;
    float* w       = (float*)d_ws;        // 128 floats
    float* partial = (float*)d_ws + NCLS; // BLOCKS floats

    prep_kernel<<<1, 128, 0, stream>>>(La, lam, w);

    // n4 = 8388608 float4s = BLOCKS * BCHUNK exactly for the bench shape
    loss_kernel<<<BLOCKS, 256, 0, stream>>>((const float4*)y_pred,
                                            (const float4*)y_true,
                                            w, partial);

    final_kernel<<<1, 256, 0, stream>>>(partial, out);
}

// Round 9
// 267.435 us; speedup vs baseline: 1.0660x; 1.0660x over previous
//
#include <hip/hip_runtime.h>

#define NCLS 128
#define HLVL 4
#define BLOCKS 8192
#define CHUNK 1024          // float4s per block per array (16 KB)

typedef float v4f __attribute__((ext_vector_type(4)));
typedef const __attribute__((address_space(1))) void* gas_t;
typedef __attribute__((address_space(3))) void* las_t;

// s_waitcnt with vmcnt(n); expcnt/lgkmcnt = don't-care (gfx9 encoding)
#define WCNT(n) __builtin_amdgcn_s_waitcnt(((n) & 15) | 0x70 | 0xF00 | (((n) >> 4) << 14))

// Prep: w[c] = (1/128) * sum_l La[l,c] * lam[l] into d_ws[0..127].
__global__ void prep_kernel(const float* __restrict__ La,
                            const float* __restrict__ lam,
                            float* __restrict__ w) {
    int c = threadIdx.x;
    if (c < NCLS) {
        float acc = 0.f;
#pragma unroll
        for (int l = 0; l < HLVL; ++l) acc += La[l * NCLS + c] * lam[l];
        w[c] = acc * (1.0f / (float)NCLS);
    }
}

// R9 (= R8 compile-fixed): DUAL-RETURN-PATH hybrid. Evidence: all VGPR-load
// variants cap at ~3.4 TB/s read; LDS-DMA (R7) showed ~2x per-wave
// efficiency at 34% occ. Theory: TCP->VGPR and TCP->LDS are separate return
// ports with separate caps. Route yt via global_load_lds DMA (16 KB LDS,
// single-buffered, wave-local readback -> no __syncthreads) and yp via nt
// VGPR loads, concurrently. If caps are per-path, throughput adds; if
// upstream, flat.
//   t*softplus(-x) + (1-t)*softplus(x) = log1p(exp(-|x|)) + max(x,0) - t*x
//   log1p(exp(-a)) = ln2 * log2(1 + 2^(-a*log2e))  -> v_exp_f32 + v_log_f32
// Leg stride 256 float4 = 1024 floats == 0 mod 128; block base 4096 floats
// == 0 mod 128 -> each thread's 4 class weights are invariant registers.
__global__ __launch_bounds__(256) void loss_kernel(const v4f* __restrict__ yp,
                                                   const v4f* __restrict__ yt,
                                                   const float* __restrict__ w,
                                                   float* __restrict__ partial) {
    __shared__ v4f lt[4][256];             // 16 KB staged yt
    const float LOG2E = 1.44269504088896340736f;
    const float LN2   = 0.69314718055994530942f;

    int t = threadIdx.x;
    int wbase = t & ~63;                   // wave-uniform LDS base lane
    int b = blockIdx.x * CHUNK + t;        // first float4 index

    int cbase = (t * 4) & (NCLS - 1);      // invariant class offset
    v4f w4 = *(const v4f*)(w + cbase);
    float wv[4] = {w4.x, w4.y, w4.z, w4.w};
    float wl[4] = {w4.x * LN2, w4.y * LN2, w4.z * LN2, w4.w * LN2};

    // 1) yt -> LDS via DMA (4 wave-instructions, lane scatter = lane*16)
#pragma unroll
    for (int r = 0; r < 4; ++r)
        __builtin_amdgcn_global_load_lds((gas_t)(yt + b + r * 256),
                                         (las_t)&lt[r][wbase], 16, 0, 0);
    // 2) yp -> VGPRs via nontemporal loads (4 more vmem in flight)
    v4f x[4];
#pragma unroll
    for (int r = 0; r < 4; ++r)
        x[r] = __builtin_nontemporal_load(yp + b + r * 256);

    // 3) drain both paths; clobber pins LDS reads below / loads above
    WCNT(0);
    __asm__ volatile("" ::: "memory");

    // 4) compute: each thread reads back only its own staged 16 B
    float acc[4] = {0.f, 0.f, 0.f, 0.f};
#pragma unroll
    for (int r = 0; r < 4; ++r) {
        v4f t4 = lt[r][t];
        float xs[4] = {x[r].x, x[r].y, x[r].z, x[r].w};
        float ts[4] = {t4.x, t4.y, t4.z, t4.w};
#pragma unroll
        for (int j = 0; j < 4; ++j) {
            float xv = xs[j];
            float e  = __builtin_amdgcn_exp2f(-fabsf(xv) * LOG2E);
            float l2 = __builtin_amdgcn_logf(1.0f + e);
            float rr = fmaf(-ts[j], xv, fmaxf(xv, 0.f));
            acc[j] = fmaf(l2, wl[j], acc[j]);
            acc[j] = fmaf(rr, wv[j], acc[j]);
        }
    }
    float a = (acc[0] + acc[1]) + (acc[2] + acc[3]);

    // wave-64 shuffle reduction
#pragma unroll
    for (int off = 32; off > 0; off >>= 1)
        a += __shfl_down(a, off, 64);

    __shared__ float bsum[4];  // 256 threads = 4 waves
    if ((t & 63) == 0) bsum[t >> 6] = a;
    __syncthreads();
    if (t == 0)
        partial[blockIdx.x] = (bsum[0] + bsum[1]) + (bsum[2] + bsum[3]);
}

// Final: reduce BLOCKS partials -> out[0].
__global__ __launch_bounds__(256) void final_kernel(const float* __restrict__ partial,
                                                    float* __restrict__ out) {
    int t = threadIdx.x;
    float a = 0.f;
#pragma unroll
    for (int k = 0; k < BLOCKS / 256; ++k)
        a += partial[t + k * 256];
#pragma unroll
    for (int off = 32; off > 0; off >>= 1)
        a += __shfl_down(a, off, 64);
    __shared__ float bsum[4];
    if ((t & 63) == 0) bsum[t >> 6] = a;
    __syncthreads();
    if (t == 0)
        out[0] = (bsum[0] + bsum[1]) + (bsum[2] + bsum[3]);
}

extern "C" void kernel_launch(void* const* d_in, const int* in_sizes, int n_in,
                              void* d_out, int out_size, void* d_ws, size_t ws_size,
                              hipStream_t stream) {
    const float* y_pred = (const float*)d_in[0];
    const float* y_true = (const float*)d_in[1];
    const float* La     = (const float*)d_in[2];
    const float* lam    = (const float*)d_in[3];
    float* out = (float*)d_out;
    float* w       = (float*)d_ws;        // 128 floats
    float* partial = (float*)d_ws + NCLS; // BLOCKS floats

    prep_kernel<<<1, 128, 0, stream>>>(La, lam, w);

    // n4 = 8388608 float4s = BLOCKS * CHUNK exactly for the bench shape
    loss_kernel<<<BLOCKS, 256, 0, stream>>>((const v4f*)y_pred,
                                            (const v4f*)y_true,
                                            w, partial);

    final_kernel<<<1, 256, 0, stream>>>(partial, out);
}